// Round 1
// baseline (234.740 us; speedup 1.0000x reference)
//
#include <hip/hip_runtime.h>

// B=8, L=1024, H=1024, NH=16, HD=64. fp32 I/O, bf16 MFMA internals.
// Pipeline: cvt3     : x,w_qkv,w_out fp32 -> bf16                  (~13 us)
//           gemm8p<0>: qk = x@w_qkv^T cols<2048; V scatters to Vt  (51.5 GF)
//           attn     : no-max softmax flash attn, S^T trick        (34.4 GF)
//           gemm8p<1>: out = O@w_out^T + b_out (fp32 out)          (17.2 GF)
// R11 (gemm): replace the 2-phase 128x128 gemm16 (769 TF, MfmaUtil 32%) with
// a T3+T4+T5 deep-pipelined gemm8p: BM=256 BN=128 BK=64, 512 thr (8 waves,
// 4x2, per-wave 64x64, acc[4][4]), ring of 3 LDS buffers (144 KB), 2 phases
// per K-tile (16 MFMA each), raw s_barrier + counted s_waitcnt vmcnt(6)
// (never 0 in the main loop: next tile's 6 global_load_lds stay in flight
// across barriers), s_setprio(1) around MFMA clusters.
// Staging ring: tile t+2 -> buf (t+2)%3 == (t-1)%3, whose last reader was
// slot t-1 (all ds_reads lgkm-drained before that slot's end barrier), so
// issuing during slot t is race-free. End-of-slot vmcnt(6) + barrier proves
// tile t+1 landed for ALL waves before slot t+1 reads it.
// Grids: QKV 24x32 = 768 blocks = exactly 3 rounds at 1 block/CU (no tail);
// out-proj 8x32 = 256 blocks = exactly 1 round. XCD-contiguous swizzle
// (nwg % 8 == 0 for both) groups same-A-panel blocks per XCD L2.
// Addressing (XOR chunk swizzle, pre-swizzled global src + linear LDS dst,
// MFMA frag/epilogue mapping) is carried over unchanged from the verified R10.

typedef short s16x8 __attribute__((ext_vector_type(8)));
typedef float f32x4 __attribute__((ext_vector_type(4)));
typedef unsigned int u32x2 __attribute__((ext_vector_type(2)));
typedef unsigned int u32x4 __attribute__((ext_vector_type(4)));

__device__ __forceinline__ unsigned short f2bf(float f) {   // RNE
    union { float f; unsigned u; } c; c.f = f;
    return (unsigned short)((c.u + 0x7FFFu + ((c.u >> 16) & 1u)) >> 16);
}
// pack 2 floats -> 2 bf16 (round-half-up) in 3 VALU ops via v_perm
__device__ __forceinline__ unsigned pack2bf(float a, float b) {
    union { float f; unsigned u; } ca, cb; ca.f = a; cb.f = b;
    return __builtin_amdgcn_perm(cb.u + 0x8000u, ca.u + 0x8000u, 0x07060302u);
}

#define GLOAD_LDS(g, l) __builtin_amdgcn_global_load_lds( \
    (const __attribute__((address_space(1))) void*)(g),   \
    (__attribute__((address_space(3))) void*)(l), 16, 0, 0)

// ---------------------------------------------------------------------------
// fp32 -> bf16 convert for the three input tensors.
// ---------------------------------------------------------------------------
__global__ __launch_bounds__(256) void cvt3(
    const float* __restrict__ s0, unsigned short* __restrict__ d0, int n0,
    const float* __restrict__ s1, unsigned short* __restrict__ d1, int n1,
    const float* __restrict__ s2, unsigned short* __restrict__ d2, int n2)
{
    long i = ((long)blockIdx.x * 256 + threadIdx.x) * 8;
    const float* s; unsigned short* d; long off;
    if (i < n0)                  { s = s0; d = d0; off = i; }
    else if (i < (long)n0 + n1)  { s = s1; d = d1; off = i - n0; }
    else                         { s = s2; d = d2; off = i - n0 - n1; }
    f32x4 a = *(const f32x4*)(s + off);
    f32x4 b = *(const f32x4*)(s + off + 4);
    u32x4 r;
    r[0] = pack2bf(a[0], a[1]); r[1] = pack2bf(a[2], a[3]);
    r[2] = pack2bf(b[0], b[1]); r[3] = pack2bf(b[2], b[3]);
    *(u32x4*)(d + off) = r;
}

// ---------------------------------------------------------------------------
// Deep-pipelined GEMM: C[M,N] = A[M,K]*B[N,K]^T, bf16 in, fp32 accum.
// K = 1024 fixed (NT = 16 K-tiles of BK=64). LDS rows of 64 bf16 = 8 x 16B
// chunks; logical chunk q of row r lives at physical chunk q ^ (r&7)
// (2-way on banks = free). Staging: pre-swizzled GLOBAL source, LINEAR LDS
// dest (global_load_lds requirement), swizzled ds_read -> involution matches.
// EPI=0: cols<1024 (Q) -> Cq bf16 scaled 0.125*log2(e); 1024..2047 (K) -> Cq
//        unscaled; >=2048 (V) packed-scatter to Cv = Vt[(b*16+h)*64+d][l].
// EPI=1: Cf fp32 + bias.
// ---------------------------------------------------------------------------
template<int EPI>
__global__ __launch_bounds__(512, 2) void gemm8p(
    const unsigned short* __restrict__ A, const unsigned short* __restrict__ Bm,
    unsigned short* __restrict__ Cq, unsigned short* __restrict__ Cv,
    float* __restrict__ Cf, const float* __restrict__ bias, int N)
{
    __shared__ unsigned short As[3 * 256 * 64];   // 96 KB: 3-buffer ring, A tile 256x64
    __shared__ unsigned short Bs[3 * 128 * 64];   // 48 KB: B tile 128x64
    const int tid = threadIdx.x, lane = tid & 63, wave = tid >> 6;
    const int quad = lane >> 4, l16 = lane & 15;
    const int wr = (wave >> 1) * 64;              // wave's M offset (4 waves in M)
    const int wc = (wave & 1) * 64;               // wave's N offset (2 waves in N)

    const int gx = gridDim.x, nwg = gx * gridDim.y;
    int wg = blockIdx.y * gx + blockIdx.x;
    wg = (wg & 7) * (nwg >> 3) + (wg >> 3);       // XCD-contiguous (nwg % 8 == 0)
    const int n0 = (wg % gx) * 128, m0 = (wg / gx) * 256;

    // staging addresses: thread covers row prow (64 rows / issue), chunk qch
    // (pre-swizzled in GLOBAL so the linear LDS dst ends up swizzled)
    const int prow = tid >> 3;
    const int qch  = (tid & 7) ^ (prow & 7);
    const unsigned short* gA[4];
    const unsigned short* gB[2];
    #pragma unroll
    for (int c = 0; c < 4; ++c)
        gA[c] = A + (size_t)(m0 + c * 64 + prow) * 1024 + qch * 8;
    #pragma unroll
    for (int c = 0; c < 2; ++c)
        gB[c] = Bm + (size_t)(n0 + c * 64 + prow) * 1024 + qch * 8;
    unsigned short* dA = As + tid * 8;            // wave-linear: base + lane*16B
    unsigned short* dB = Bs + tid * 8;

    // prologue: stage tiles 0,1 (12 loads); tile 0 landed when 6 newest remain
    #pragma unroll
    for (int t = 0; t < 2; ++t) {
        #pragma unroll
        for (int c = 0; c < 4; ++c) GLOAD_LDS(gA[c] + t * 64, dA + t * 16384 + c * 4096);
        #pragma unroll
        for (int c = 0; c < 2; ++c) GLOAD_LDS(gB[c] + t * 64, dB + t * 8192 + c * 4096);
    }
    asm volatile("s_waitcnt vmcnt(6)" ::: "memory");
    __builtin_amdgcn_s_barrier();

    f32x4 acc[4][4] = {};
    const int sw = l16 & 7;                       // frag-read swizzle (row&7 == l16&7)
    int rA = 0, rB = 0;                           // compute buffer offsets (t%3)
    int r2A = 2 * 16384, r2B = 2 * 8192;          // stage target offsets ((t+2)%3)
    for (int t = 0; t < 16; ++t) {
        const unsigned short* pa = As + rA + (wr + l16) * 64;
        const unsigned short* pb = Bs + rB + (wc + l16) * 64;
        s16x8 af[4], bf[4];
        // ---- phase 0: k = 0..31 of this K-tile ----
        {
            const int pc = (quad ^ sw) * 8;
            #pragma unroll
            for (int i = 0; i < 4; ++i) af[i] = *(const s16x8*)(pa + i * 1024 + pc);
            #pragma unroll
            for (int j = 0; j < 4; ++j) bf[j] = *(const s16x8*)(pb + j * 1024 + pc);
        }
        if (t < 14) {                              // stage(t+2) part 1 (A c0..c2)
            GLOAD_LDS(gA[0] + (t + 2) * 64, dA + r2A);
            GLOAD_LDS(gA[1] + (t + 2) * 64, dA + r2A + 4096);
            GLOAD_LDS(gA[2] + (t + 2) * 64, dA + r2A + 8192);
        }
        __builtin_amdgcn_s_barrier();
        __builtin_amdgcn_s_setprio(1);
        #pragma unroll
        for (int i = 0; i < 4; ++i)
            #pragma unroll
            for (int j = 0; j < 4; ++j)
                acc[i][j] = __builtin_amdgcn_mfma_f32_16x16x32_bf16(af[i], bf[j], acc[i][j], 0, 0, 0);
        __builtin_amdgcn_s_setprio(0);
        __builtin_amdgcn_s_barrier();
        // ---- phase 1: k = 32..63 ----
        {
            const int pc = ((4 + quad) ^ sw) * 8;
            #pragma unroll
            for (int i = 0; i < 4; ++i) af[i] = *(const s16x8*)(pa + i * 1024 + pc);
            #pragma unroll
            for (int j = 0; j < 4; ++j) bf[j] = *(const s16x8*)(pb + j * 1024 + pc);
        }
        if (t < 14) {                              // stage(t+2) part 2 (A c3, B c0..c1)
            GLOAD_LDS(gA[3] + (t + 2) * 64, dA + r2A + 12288);
            GLOAD_LDS(gB[0] + (t + 2) * 64, dB + r2B);
            GLOAD_LDS(gB[1] + (t + 2) * 64, dB + r2B + 4096);
        }
        __builtin_amdgcn_s_barrier();
        __builtin_amdgcn_s_setprio(1);
        #pragma unroll
        for (int i = 0; i < 4; ++i)
            #pragma unroll
            for (int j = 0; j < 4; ++j)
                acc[i][j] = __builtin_amdgcn_mfma_f32_16x16x32_bf16(af[i], bf[j], acc[i][j], 0, 0, 0);
        __builtin_amdgcn_s_setprio(0);
        // end of slot: prove tile t+1 landed (6 newest = tile t+2 stay in flight)
        if (t < 14)       asm volatile("s_waitcnt vmcnt(6)" ::: "memory");
        else if (t == 14) asm volatile("s_waitcnt vmcnt(0)" ::: "memory");
        __builtin_amdgcn_s_barrier();
        rA  = (rA  == 2 * 16384) ? 0 : rA  + 16384;
        rB  = (rB  == 2 * 8192)  ? 0 : rB  + 8192;
        r2A = (r2A == 2 * 16384) ? 0 : r2A + 16384;
        r2B = (r2B == 2 * 8192)  ? 0 : r2B + 8192;
    }

    // epilogue: C/D layout col=lane&15, row=quad*4+reg
    if (EPI == 1) {
        #pragma unroll
        for (int j = 0; j < 4; ++j) {
            int col = n0 + wc + j * 16 + l16;
            float bv = bias[col];
            #pragma unroll
            for (int i = 0; i < 4; ++i)
                #pragma unroll
                for (int r = 0; r < 4; ++r)
                    Cf[(size_t)(m0 + wr + i * 16 + quad * 4 + r) * N + col] = acc[i][j][r] + bv;
        }
    } else if (n0 < 2048) {
        // Q region: prefold softmax scale (1/8) and log2(e) for native exp2
        const float qs = (n0 < 1024) ? 0.18033688f : 1.0f;   // 0.125*log2(e)
        #pragma unroll
        for (int j = 0; j < 4; ++j) {
            int col = n0 + wc + j * 16 + l16;
            #pragma unroll
            for (int i = 0; i < 4; ++i)
                #pragma unroll
                for (int r = 0; r < 4; ++r)
                    Cq[(size_t)(m0 + wr + i * 16 + quad * 4 + r) * 2048 + col] = f2bf(acc[i][j][r] * qs);
        }
    } else {
        // V region: lane's r=0..3 are 4 consecutive l -> one 8B packed store
        #pragma unroll
        for (int j = 0; j < 4; ++j) {
            int dcol = n0 + wc + j * 16 + l16 - 2048;
            int hh = dcol >> 6, dd = dcol & 63;
            #pragma unroll
            for (int i = 0; i < 4; ++i) {
                int row = m0 + wr + i * 16 + quad * 4;
                int bb = row >> 10, l = row & 1023;
                u32x2 pw;
                pw[0] = pack2bf(acc[i][j][0], acc[i][j][1]);
                pw[1] = pack2bf(acc[i][j][2], acc[i][j][3]);
                *(u32x2*)(Cv + (size_t)((bb * 16 + hh) * 64 + dd) * 1024 + l) = pw;
            }
        }
    }
}

// ---------------------------------------------------------------------------
// Flash attention, no-max softmax (Q pre-scaled by 0.125*log2e -> bare exp2),
// S^T trick with kv-permuted K staging so P's packed C-layout registers are
// directly the PV A-fragments (no P LDS round-trip).
// K staging permutation: LDS row rho = 16t+4u+r holds kv = 32(t>>1)+8u+4(t&1)+r.
// 64 q-rows/block, grid (16 qtile, 128 bh) = 2048 blocks = 8 blocks/CU
// = 32 waves/CU (HW max). LDS 16.4 KB.
// ---------------------------------------------------------------------------
__global__ __launch_bounds__(256) void attn(
    const unsigned short* __restrict__ qk, const unsigned short* __restrict__ Vt,
    unsigned short* __restrict__ O)
{
    __shared__ unsigned short Ks[64 * 64];   // [rho][d] kv-permuted, swizzled
    __shared__ unsigned short Vs[64 * 64];   // [d][kv]  natural, swizzled

    const int bh = blockIdx.y, b = bh >> 4, hh = bh & 15;
    const int q0 = blockIdx.x * 64;
    const int tid = threadIdx.x, lane = tid & 63, wave = tid >> 6;
    const int quad = lane >> 4, l16 = lane & 15;

    // Q frags direct from global: B-operand, n=q=wave*16+l16, k=s*32+quad*8
    const unsigned short* qrow =
        qk + (size_t)(b * 1024 + q0 + wave * 16 + l16) * 2048 + hh * 64;
    s16x8 qf[2];
    qf[0] = *(const s16x8*)(qrow + quad * 8);
    qf[1] = *(const s16x8*)(qrow + 32 + quad * 8);

    // Staging: wave covers LDS rows rho0 = wave*16+rl and rho1 = rho0+8
    // (rl = lane>>3); chunk swizzle qc = (lane&7) ^ (rho&7), rho&7 == rl.
    // K source rows are the PERMUTED kv for each rho (t = wave for both).
    const int rl = lane >> 3;
    const int qc = (lane & 7) ^ rl;
    const int u0 = rl >> 2, r0 = rl & 3;
    const int kvbase = 32 * (wave >> 1) + 4 * (wave & 1) + r0;
    const int kv0 = kvbase + 8 * u0;          // for LDS row wave*16 + rl
    const int kv1 = kvbase + 8 * (2 + u0);    // for LDS row wave*16 + 8 + rl
    const unsigned short* srcK0 = qk + (size_t)(b * 1024 + kv0) * 2048 + 1024 + hh * 64 + qc * 8;
    const unsigned short* srcK1 = qk + (size_t)(b * 1024 + kv1) * 2048 + 1024 + hh * 64 + qc * 8;
    const unsigned short* srcV0 = Vt + (size_t)(bh * 64 + wave * 16 + rl) * 1024 + qc * 8;
    const unsigned short* srcV1 = Vt + (size_t)(bh * 64 + wave * 16 + 8 + rl) * 1024 + qc * 8;
    unsigned short* dK0 = Ks + (wave * 16 + rl) * 64 + (lane & 7) * 8;
    unsigned short* dK1 = Ks + (wave * 16 + 8 + rl) * 64 + (lane & 7) * 8;
    unsigned short* dV0 = Vs + (wave * 16 + rl) * 64 + (lane & 7) * 8;
    unsigned short* dV1 = Vs + (wave * 16 + 8 + rl) * 64 + (lane & 7) * 8;

    const int sw = l16 & 7;   // frag-read swizzle

    f32x4 Oacc[4] = {};
    float lsum = 0.0f;

    for (int kv = 0; kv < 1024; kv += 64) {
        __syncthreads();
        GLOAD_LDS(srcK0, dK0);
        GLOAD_LDS(srcK1, dK1);
        GLOAD_LDS(srcV0, dV0);
        GLOAD_LDS(srcV1, dV1);
        srcK0 += (size_t)64 * 2048; srcK1 += (size_t)64 * 2048;
        srcV0 += 64; srcV1 += 64;
        __syncthreads();   // vmcnt(0) drain -> K,V in LDS

        // S^T = K Q^T : tile t rows = permuted kv, col q = l16
        f32x4 Sacc[4] = {};
        #pragma unroll
        for (int t = 0; t < 4; ++t) {
            #pragma unroll
            for (int s = 0; s < 2; ++s) {
                s16x8 kf = *(const s16x8*)(Ks + (t * 16 + l16) * 64 + ((s * 4 + quad) ^ sw) * 8);
                Sacc[t] = __builtin_amdgcn_mfma_f32_16x16x32_bf16(kf, qf[s], Sacc[t], 0, 0, 0);
            }
        }
        // p = 2^s; per-lane row-sum; pack pairs (these ARE the PV A-frags)
        unsigned upw[4][2];
        #pragma unroll
        for (int t = 0; t < 4; ++t) {
            float p0 = __builtin_amdgcn_exp2f(Sacc[t][0]);
            float p1 = __builtin_amdgcn_exp2f(Sacc[t][1]);
            float p2 = __builtin_amdgcn_exp2f(Sacc[t][2]);
            float p3 = __builtin_amdgcn_exp2f(Sacc[t][3]);
            lsum += (p0 + p1) + (p2 + p3);
            upw[t][0] = pack2bf(p0, p1);
            upw[t][1] = pack2bf(p2, p3);
        }
        // O += P V^T : A = packed P (register), B = Vs[n=d] (natural)
        #pragma unroll
        for (int s = 0; s < 2; ++s) {
            u32x4 aw;
            aw[0] = upw[2 * s][0];     aw[1] = upw[2 * s][1];
            aw[2] = upw[2 * s + 1][0]; aw[3] = upw[2 * s + 1][1];
            s16x8 pf;
            __builtin_memcpy(&pf, &aw, 16);
            #pragma unroll
            for (int jd = 0; jd < 4; ++jd) {
                s16x8 vf = *(const s16x8*)(Vs + (jd * 16 + l16) * 64 + ((s * 4 + quad) ^ sw) * 8);
                Oacc[jd] = __builtin_amdgcn_mfma_f32_16x16x32_bf16(pf, vf, Oacc[jd], 0, 0, 0);
            }
        }
    }

    // row-sum reduce + write (sum over quads is permutation-invariant)
    lsum += __shfl_xor(lsum, 16, 64);
    lsum += __shfl_xor(lsum, 32, 64);
    float rinv[4];
    #pragma unroll
    for (int r = 0; r < 4; ++r)
        rinv[r] = 1.0f / __shfl(lsum, quad * 4 + r, 64);
    #pragma unroll
    for (int j = 0; j < 4; ++j)
        #pragma unroll
        for (int r = 0; r < 4; ++r) {
            int row = q0 + wave * 16 + quad * 4 + r;
            int col = hh * 64 + j * 16 + l16;
            O[(size_t)(b * 1024 + row) * 1024 + col] = f2bf(Oacc[j][r] * rinv[r]);
        }
}

extern "C" void kernel_launch(void* const* d_in, const int* in_sizes, int n_in,
                              void* d_out, int out_size, void* d_ws, size_t ws_size,
                              hipStream_t stream) {
    const float* x     = (const float*)d_in[0];   // [8192,1024]
    const float* w_qkv = (const float*)d_in[1];   // [3072,1024]
    const float* w_out = (const float*)d_in[2];   // [1024,1024]
    const float* b_out = (const float*)d_in[3];   // [1024]
    float* out = (float*)d_out;                   // [8192,1024] fp32

    const int nx = 8192 * 1024, nwq = 3072 * 1024, nwo = 1024 * 1024;
    unsigned short* xb  = (unsigned short*)d_ws;          // 16.8 MB (dead after gemm1)
    unsigned short* wqb = xb + nx;                        //  6.3 MB
    unsigned short* wob = wqb + nwq;                      //  2.1 MB
    unsigned short* qkb = wob + nwo;                      // [8192,2048] Q|K, 33.6 MB
    unsigned short* Vt  = qkb + (size_t)8192 * 2048;      // [128*64,1024], 16.8 MB
    unsigned short* Ob  = xb;                             // alias: xb dead after gemm1

    cvt3<<<6144, dim3(256), 0, stream>>>(x, xb, nx, w_qkv, wqb, nwq, w_out, wob, nwo);
    gemm8p<0><<<dim3(24, 32), dim3(512), 0, stream>>>(xb, wqb, qkb, Vt, nullptr, nullptr, 3072);
    attn<<<dim3(16, 128), dim3(256), 0, stream>>>(qkb, Vt, Ob);
    gemm8p<1><<<dim3(8, 32), dim3(512), 0, stream>>>(Ob, wob, nullptr, nullptr, out, b_out, 1024);
}